// Round 2
// 142.461 us; speedup vs baseline: 1.0193x; 1.0193x over previous
//
#include <hip/hip_runtime.h>

typedef unsigned short u16;
typedef unsigned int u32;
typedef _Float16 h8 __attribute__((ext_vector_type(8)));
typedef __fp16 fp16x2 __attribute__((ext_vector_type(2)));
typedef float f32x16 __attribute__((ext_vector_type(16)));

__device__ inline f32x16 zero16() {
    f32x16 v;
#pragma unroll
    for (int i = 0; i < 16; ++i) v[i] = 0.f;
    return v;
}
__device__ inline u16 f2h_bits(float f) {
    _Float16 h = (_Float16)f;
    u16 u;
    __builtin_memcpy(&u, &h, 2);
    return u;
}
__device__ inline void load_lds16(const u16* g, u16* l) {
    __builtin_amdgcn_global_load_lds((const __attribute__((address_space(1))) u32*)(const void*)g,
                                     (__attribute__((address_space(3))) u32*)(void*)l, 16, 0, 0);
}

// ---------- merged prep: X f32->f16 (blocks 0..2047), W f32 [1024][3072] -> Wt f16 [3072][1024] ----------
__global__ void __launch_bounds__(256) prep(const float* __restrict__ X, const float* __restrict__ W,
                                            u16* __restrict__ Xh, u16* __restrict__ Wt) {
    __shared__ __attribute__((aligned(16))) u16 tile[64][72];
    int bb = blockIdx.x;
    int tid = threadIdx.x;
    if (bb < 2048) {
        int i = (bb * 256 + tid) * 8;
        float4 a = *(const float4*)(X + i);
        float4 b = *(const float4*)(X + i + 4);
        u16 t[8] = {f2h_bits(a.x), f2h_bits(a.y), f2h_bits(a.z), f2h_bits(a.w),
                    f2h_bits(b.x), f2h_bits(b.y), f2h_bits(b.z), f2h_bits(b.w)};
        *(uint4*)(Xh + i) = *(uint4*)t;
        return;
    }
    bb -= 2048;
    int tn0 = (bb % 48) * 64, tk0 = (bb / 48) * 64;
#pragma unroll
    for (int i = 0; i < 4; ++i) {
        int e = (i * 256 + tid) * 4;
        int r = e >> 6, c = e & 63;
        float4 v = *(const float4*)(W + (size_t)(tk0 + r) * 3072 + tn0 + c);
        tile[r][c + 0] = f2h_bits(v.x);
        tile[r][c + 1] = f2h_bits(v.y);
        tile[r][c + 2] = f2h_bits(v.z);
        tile[r][c + 3] = f2h_bits(v.w);
    }
    __syncthreads();
#pragma unroll
    for (int i = 0; i < 2; ++i) {
        int e = (i * 256 + tid) * 8;
        int r = e >> 6, c = e & 63;
        u16 tmp[8];
#pragma unroll
        for (int j = 0; j < 8; ++j) tmp[j] = tile[c + j][r];
        *(uint4*)(Wt + (size_t)(tn0 + r) * 1024 + tk0 + c) = *(uint4*)tmp;
    }
}

// ---------- QKV GEMM, BK=64 (half the barrier drains), XOR-swizzled LDS ----------
// Qf/Kf[bh][kt][gc=d>>3][row=t&31][c=d&7]  (Q pre-scaled by 0.125)
// Vf[bh][kt][gc2=(t&31)>>3][d][c=t&7]
__global__ void __launch_bounds__(256) qkv_gemm(const u16* __restrict__ Xh, const u16* __restrict__ Wt,
                                                const float* __restrict__ bias, u16* __restrict__ Qf,
                                                u16* __restrict__ Kf, u16* __restrict__ Vf) {
    __shared__ __attribute__((aligned(16))) u16 As[128 * 64];  // 16 KB
    __shared__ __attribute__((aligned(16))) u16 Bs[128 * 64];  // 16 KB
    int m0 = blockIdx.x * 128, n0 = blockIdx.y * 128;
    int tid = threadIdx.x, wave = tid >> 6, lane = tid & 63;
    int lane31 = lane & 31, half = lane >> 5;
    int wm = wave & 1, wn = wave >> 1;
    int sw = (lane31 >> 1) & 7;  // 3-bit swizzle; rows +32/+64 shift by 0 mod 8 after >>1

    f32x16 acc00 = zero16(), acc01 = zero16(), acc10 = zero16(), acc11 = zero16();

    for (int k0 = 0; k0 < 1024; k0 += 64) {
        __syncthreads();
#pragma unroll
        for (int i = 0; i < 4; ++i) {
            int e = (i * 256 + tid) * 8;  // [0, 8192)
            int r = e >> 6, c = e & 63;
            int gs = ((c >> 3) ^ ((r >> 1) & 7)) * 8;
            load_lds16(Xh + (size_t)(m0 + r) * 1024 + k0 + gs, &As[e]);
            load_lds16(Wt + (size_t)(n0 + r) * 1024 + k0 + gs, &Bs[e]);
        }
        __syncthreads();
#pragma unroll
        for (int kk = 0; kk < 4; ++kk) {
            int ga = ((kk * 2 + half) ^ sw) * 8;
            h8 a0 = *(const h8*)&As[(wm * 64 + lane31) * 64 + ga];
            h8 a1 = *(const h8*)&As[(wm * 64 + 32 + lane31) * 64 + ga];
            h8 b0 = *(const h8*)&Bs[(wn * 64 + lane31) * 64 + ga];
            h8 b1 = *(const h8*)&Bs[(wn * 64 + 32 + lane31) * 64 + ga];
            acc00 = __builtin_amdgcn_mfma_f32_32x32x16_f16(a0, b0, acc00, 0, 0, 0);
            acc01 = __builtin_amdgcn_mfma_f32_32x32x16_f16(a0, b1, acc01, 0, 0, 0);
            acc10 = __builtin_amdgcn_mfma_f32_32x32x16_f16(a1, b0, acc10, 0, 0, 0);
            acc11 = __builtin_amdgcn_mfma_f32_32x32x16_f16(a1, b1, acc11, 0, 0, 0);
        }
    }

#pragma unroll
    for (int mi = 0; mi < 2; ++mi) {
#pragma unroll
        for (int ni = 0; ni < 2; ++ni) {
            const f32x16& acc = mi == 0 ? (ni == 0 ? acc00 : acc01) : (ni == 0 ? acc10 : acc11);
            int n = n0 + wn * 64 + ni * 32 + lane31;
            int mbase = m0 + wm * 64 + mi * 32;
            int bb = mbase >> 11, tb = mbase & 2047;
            float bv = bias[n];
            int n2 = n & 1023;
            int h = n2 >> 6, d = n2 & 63;
            if (n < 2048) {
                float sc = (n < 1024) ? 0.125f : 1.0f;
                u16* base = (n < 1024 ? Qf : Kf) +
                            (size_t)(bb * 16 + h) * 131072 + (tb >> 5) * 2048 + (d >> 3) * 256 + (d & 7);
#pragma unroll
                for (int r = 0; r < 16; ++r) {
                    int row = (r & 3) + 8 * (r >> 2) + 4 * half;
                    base[row * 8] = f2h_bits((acc[r] + bv) * sc);
                }
            } else {
                u16* vbase = Vf + (size_t)(bb * 16 + h) * 131072 + (tb >> 5) * 2048 + d * 8 + 4 * half;
#pragma unroll
                for (int rq = 0; rq < 4; ++rq) {
                    u16 q4[4];
#pragma unroll
                    for (int j = 0; j < 4; ++j) q4[j] = f2h_bits(acc[4 * rq + j] + bv);
                    *(ushort4*)(vbase + rq * 512) = *(ushort4*)q4;
                }
            }
        }
    }
}

// ---------- attention v7: permlane32_swap pack, diagonal-only masking, 2-set rotation, parallel epilogue ----------
__global__ void __launch_bounds__(256) attn(const u16* __restrict__ Qf, const u16* __restrict__ Kf,
                                            const u16* __restrict__ Vf, float* __restrict__ out) {
    __shared__ float4 red[4 * 8 * 64];  // 32 KB
    int bh = blockIdx.x;                // fast dim: id%8 = bh%8 -> same-bh on one XCD
    int tt = 63 - blockIdx.y;           // heavy q-tiles dispatch first (better tail)
    int b = bh >> 4, h = bh & 15;
    int tid = threadIdx.x, w = tid >> 6, lane = tid & 63;
    int l31 = lane & 31, half = lane >> 5;

    const u16* Qbh = Qf + (size_t)bh * 131072;
    const u16* Kbh = Kf + (size_t)bh * 131072;
    const u16* Vbh = Vf + (size_t)bh * 131072;

    int qset = tt * 32;
    const u16* qp = Qbh + tt * 2048 + half * 256 + l31 * 8;
    h8 aQ[4];
#pragma unroll
    for (int kk = 0; kk < 4; ++kk) aQ[kk] = *(const h8*)(qp + kk * 512);

    int nkt = tt + 1;
    int kt0 = (nkt * w) >> 2;
    int kt1 = (nkt * (w + 1)) >> 2;
    f32x16 y0 = zero16(), y1 = zero16();
    int qg = qset + l31;

    auto LOADKV = [&](int kt, h8* Kd, h8* Vd) {
        const u16* kp = Kbh + kt * 2048 + half * 256 + l31 * 8;
        const u16* vp = Vbh + kt * 2048 + half * 512 + l31 * 8;
#pragma unroll
        for (int kk = 0; kk < 4; ++kk) Kd[kk] = *(const h8*)(kp + kk * 512);
        Vd[0] = *(const h8*)vp;
        Vd[1] = *(const h8*)(vp + 1024);
        Vd[2] = *(const h8*)(vp + 256);
        Vd[3] = *(const h8*)(vp + 1280);
    };

    auto TILE = [&](int kt, const h8* Kc, const h8* Vc) {
        f32x16 sT = zero16();
#pragma unroll
        for (int kk = 0; kk < 4; ++kk)
            sT = __builtin_amdgcn_mfma_f32_32x32x16_f16(Kc[kk], aQ[kk], sT, 0, 0, 0);

        u32 pk[8];
        if (kt == tt) {  // only the diagonal tile needs causal masking (wave-uniform branch)
            int cbase = qg - kt * 32 - 4 * half;
#pragma unroll
            for (int j = 0; j < 8; ++j) {
                int row0 = ((2 * j) & 3) + 8 * (j >> 1);
                float v0 = (row0 <= cbase) ? fmaxf(sT[2 * j], 0.f) : 0.f;
                float v1 = (row0 + 1 <= cbase) ? fmaxf(sT[2 * j + 1], 0.f) : 0.f;
                fp16x2 c2 = __builtin_amdgcn_cvt_pkrtz(v0, v1);
                __builtin_memcpy(&pk[j], &c2, 4);
            }
        } else {
#pragma unroll
            for (int j = 0; j < 8; ++j) {
                fp16x2 c2 = __builtin_amdgcn_cvt_pkrtz(fmaxf(sT[2 * j], 0.f), fmaxf(sT[2 * j + 1], 0.f));
                __builtin_memcpy(&pk[j], &c2, 4);
            }
        }
        // cross-half redistribution: one permlane32_swap fills two B-fragment words
        // (replaces 8 shfl_xor + 16 cndmask selects)
        u32 a0 = pk[0], b0 = pk[2], a1 = pk[1], b1 = pk[3];
        u32 a2 = pk[4], b2 = pk[6], a3 = pk[5], b3 = pk[7];
        asm("v_permlane32_swap_b32 %0, %1" : "+v"(a0), "+v"(b0));
        asm("v_permlane32_swap_b32 %0, %1" : "+v"(a1), "+v"(b1));
        asm("v_permlane32_swap_b32 %0, %1" : "+v"(a2), "+v"(b2));
        asm("v_permlane32_swap_b32 %0, %1" : "+v"(a3), "+v"(b3));
        u32 f0[4] = {a0, a1, b0, b1};
        u32 f1[4] = {a2, a3, b2, b3};
        h8 bP0, bP1;
        __builtin_memcpy(&bP0, f0, 16);
        __builtin_memcpy(&bP1, f1, 16);

        y0 = __builtin_amdgcn_mfma_f32_32x32x16_f16(Vc[0], bP0, y0, 0, 0, 0);
        y0 = __builtin_amdgcn_mfma_f32_32x32x16_f16(Vc[1], bP1, y0, 0, 0, 0);
        y1 = __builtin_amdgcn_mfma_f32_32x32x16_f16(Vc[2], bP0, y1, 0, 0, 0);
        y1 = __builtin_amdgcn_mfma_f32_32x32x16_f16(Vc[3], bP1, y1, 0, 0, 0);
    };

    if (kt0 < kt1) {
        h8 KA[4], VA[4], KB[4], VB[4];
        LOADKV(kt0, KA, VA);
        for (int kt = kt0; kt < kt1; kt += 2) {
            int ktn = kt + 1 < kt1 ? kt + 1 : kt1 - 1;
            LOADKV(ktn, KB, VB);           // prefetch t+1 overlapped with compute(t)
            TILE(kt, KA, VA);
            int ktn2 = kt + 2 < kt1 ? kt + 2 : kt1 - 1;
            LOADKV(ktn2, KA, VA);          // prefetch t+2 overlapped with compute(t+1)
            if (kt + 1 < kt1) TILE(kt + 1, KB, VB);
        }
    }

    // parallel epilogue: all 4 waves dump y to LDS, then 256 threads sum+store
#pragma unroll
    for (int g = 0; g < 4; ++g) {
        red[(w * 8 + g) * 64 + lane] =
            make_float4(y0[4 * g], y0[4 * g + 1], y0[4 * g + 2], y0[4 * g + 3]);
        red[(w * 8 + 4 + g) * 64 + lane] =
            make_float4(y1[4 * g], y1[4 * g + 1], y1[4 * g + 2], y1[4 * g + 3]);
    }
    __syncthreads();
#pragma unroll
    for (int ss = 0; ss < 2; ++ss) {
        int s = tid + ss * 256;  // stride-16B across lanes: bank-conflict-free
        float4 r0 = red[s], r1 = red[512 + s], r2 = red[1024 + s], r3 = red[1536 + s];
        float4 acc = make_float4(r0.x + r1.x + r2.x + r3.x, r0.y + r1.y + r2.y + r3.y,
                                 r0.z + r1.z + r2.z + r3.z, r0.w + r1.w + r2.w + r3.w);
        int gslot = s >> 6, ln = s & 63;
        int sl31 = ln & 31, shf = ln >> 5;
        int d = (gslot >> 2) * 32 + (gslot & 3) * 8 + shf * 4;
        *(float4*)(out + ((size_t)b * 2048 + qset + sl31) * 1024 + h * 64 + d) = acc;
    }
}

extern "C" void kernel_launch(void* const* d_in, const int* in_sizes, int n_in,
                              void* d_out, int out_size, void* d_ws, size_t ws_size,
                              hipStream_t stream) {
    const float* X = (const float*)d_in[0];     // [2,2048,1024] f32 (fp16 values widened)
    const float* W = (const float*)d_in[1];     // [1024,3072] f32
    const float* bias = (const float*)d_in[2];  // [3072] f32
    float* out = (float*)d_out;                 // [2,2048,1024] f32

    char* ws = (char*)d_ws;
    u16* Xh = (u16*)ws;                      // 8388608 B
    u16* Wt = (u16*)(ws + 8388608);          // 6291456 B
    u16* Qf = (u16*)(ws + 14680064);         // 8388608 B
    u16* Kf = (u16*)(ws + 23068672);         // 8388608 B
    u16* Vf = (u16*)(ws + 31457280);         // 8388608 B

    prep<<<2816, 256, 0, stream>>>(X, W, Xh, Wt);
    qkv_gemm<<<dim3(32, 24), 256, 0, stream>>>(Xh, Wt, bias, Qf, Kf, Vf);
    attn<<<dim3(32, 64), 256, 0, stream>>>(Qf, Kf, Vf, out);
}

// Round 3
// 141.426 us; speedup vs baseline: 1.0267x; 1.0073x over previous
//
#include <hip/hip_runtime.h>

typedef unsigned short u16;
typedef unsigned int u32;
typedef _Float16 h8 __attribute__((ext_vector_type(8)));
typedef __fp16 fp16x2 __attribute__((ext_vector_type(2)));
typedef float f32x16 __attribute__((ext_vector_type(16)));

__device__ inline f32x16 zero16() {
    f32x16 v;
#pragma unroll
    for (int i = 0; i < 16; ++i) v[i] = 0.f;
    return v;
}
__device__ inline u16 f2h_bits(float f) {
    _Float16 h = (_Float16)f;
    u16 u;
    __builtin_memcpy(&u, &h, 2);
    return u;
}
__device__ inline void load_lds16(const u16* g, u16* l) {
    __builtin_amdgcn_global_load_lds((const __attribute__((address_space(1))) u32*)(const void*)g,
                                     (__attribute__((address_space(3))) u32*)(void*)l, 16, 0, 0);
}

// ---------- merged prep: X f32->f16 (blocks 0..2047), W f32 [1024][3072] -> Wt f16 [3072][1024] ----------
__global__ void __launch_bounds__(256) prep(const float* __restrict__ X, const float* __restrict__ W,
                                            u16* __restrict__ Xh, u16* __restrict__ Wt) {
    __shared__ __attribute__((aligned(16))) u16 tile[64][72];
    int bb = blockIdx.x;
    int tid = threadIdx.x;
    if (bb < 2048) {
        int i = (bb * 256 + tid) * 8;
        float4 a = *(const float4*)(X + i);
        float4 b = *(const float4*)(X + i + 4);
        u16 t[8] = {f2h_bits(a.x), f2h_bits(a.y), f2h_bits(a.z), f2h_bits(a.w),
                    f2h_bits(b.x), f2h_bits(b.y), f2h_bits(b.z), f2h_bits(b.w)};
        *(uint4*)(Xh + i) = *(uint4*)t;
        return;
    }
    bb -= 2048;
    int tn0 = (bb % 48) * 64, tk0 = (bb / 48) * 64;
#pragma unroll
    for (int i = 0; i < 4; ++i) {
        int e = (i * 256 + tid) * 4;
        int r = e >> 6, c = e & 63;
        float4 v = *(const float4*)(W + (size_t)(tk0 + r) * 3072 + tn0 + c);
        tile[r][c + 0] = f2h_bits(v.x);
        tile[r][c + 1] = f2h_bits(v.y);
        tile[r][c + 2] = f2h_bits(v.z);
        tile[r][c + 3] = f2h_bits(v.w);
    }
    __syncthreads();
#pragma unroll
    for (int i = 0; i < 2; ++i) {
        int e = (i * 256 + tid) * 8;
        int r = e >> 6, c = e & 63;
        u16 tmp[8];
#pragma unroll
        for (int j = 0; j < 8; ++j) tmp[j] = tile[c + j][r];
        *(uint4*)(Wt + (size_t)(tn0 + r) * 1024 + tk0 + c) = *(uint4*)tmp;
    }
}

// ---------- QKV GEMM v2: 256x256 tile, 8 waves (2Mx4N), 4-phase counted-vmcnt pipeline ----------
// Slots per K-tile (16 KB each, staged in order): s0=B cols 0-127, s1=B cols 128-255,
// s2=A rows for phases 0,1 (row-permuted), s3=A rows for phases 2,3.
// Sync: vmcnt(2)+barrier at tile boundary (s3 may fly), vmcnt(4)+barrier mid-tile (next B0,B1 fly).
// A LDS row permutation: lds_row = mi*64 + wm*32 + l  <->  global row = wm*128 + mi*32 + l.
__global__ void __launch_bounds__(512, 2) qkv_gemm(const u16* __restrict__ Xh, const u16* __restrict__ Wt,
                                                   const float* __restrict__ bias, u16* __restrict__ Qf,
                                                   u16* __restrict__ Kf, u16* __restrict__ Vf) {
    __shared__ __attribute__((aligned(16))) u16 As[2][16384];  // 64 KB
    __shared__ __attribute__((aligned(16))) u16 Bs[2][16384];  // 64 KB
    int m0 = blockIdx.x * 256, n0 = blockIdx.y * 256;
    int tid = threadIdx.x, wave = tid >> 6, lane = tid & 63;
    int l31 = lane & 31, half = lane >> 5;
    int wm = wave & 1, wn = wave >> 1;  // 2M x 4N
    int sw = (l31 >> 1) & 7;

    // staging addresses: per thread 2 x 16B per 16 KB slot
    int e0 = tid * 8, e1 = (512 + tid) * 8;  // u16 offsets in slot
    int r0 = e0 >> 6, c0 = e0 & 63;          // r0 in [0,64)
    int r1 = e1 >> 6, c1 = e1 & 63;          // r1 in [64,128)
    int gs0 = ((c0 >> 3) ^ ((r0 >> 1) & 7)) * 8;
    int gs1 = ((c1 >> 3) ^ ((r1 >> 1) & 7)) * 8;
    int gr0 = ((r0 >> 5) & 1) * 128 + (r0 >> 6) * 32 + (r0 & 31);  // A row permutation
    int gr1 = ((r1 >> 5) & 1) * 128 + (r1 >> 6) * 32 + (r1 & 31);
    const u16* pB0_0 = Wt + (size_t)(n0 + r0) * 1024 + gs0;
    const u16* pB0_1 = Wt + (size_t)(n0 + r1) * 1024 + gs1;
    const u16* pB1_0 = pB0_0 + 128 * 1024;
    const u16* pB1_1 = pB0_1 + 128 * 1024;
    const u16* pA0_0 = Xh + (size_t)(m0 + gr0) * 1024 + gs0;
    const u16* pA0_1 = Xh + (size_t)(m0 + gr1) * 1024 + gs1;
    const u16* pA1_0 = pA0_0 + 64 * 1024;  // +64 global rows
    const u16* pA1_1 = pA0_1 + 64 * 1024;

#define SB0(nb, ko) { load_lds16(pB0_0 + (ko), &Bs[nb][e0]); load_lds16(pB0_1 + (ko), &Bs[nb][e1]); }
#define SB1(nb, ko) { load_lds16(pB1_0 + (ko), &Bs[nb][8192 + e0]); load_lds16(pB1_1 + (ko), &Bs[nb][8192 + e1]); }
#define SA0(nb, ko) { load_lds16(pA0_0 + (ko), &As[nb][e0]); load_lds16(pA0_1 + (ko), &As[nb][e1]); }
#define SA1(nb, ko) { load_lds16(pA1_0 + (ko), &As[nb][8192 + e0]); load_lds16(pA1_1 + (ko), &As[nb][8192 + e1]); }

#define SYNC(n)                                           \
    __builtin_amdgcn_sched_barrier(0);                    \
    asm volatile("s_waitcnt vmcnt(" #n ")" ::: "memory"); \
    __builtin_amdgcn_s_barrier();                         \
    __builtin_amdgcn_sched_barrier(0);

    int arow = wm * 32 + l31;
    int brow0 = (wn * 64 + l31) * 64;
    int brow1 = (wn * 64 + 32 + l31) * 64;

    f32x16 acc[4][2];
#pragma unroll
    for (int mi = 0; mi < 4; ++mi) {
        acc[mi][0] = zero16();
        acc[mi][1] = zero16();
    }
    h8 bf[2][4];

#define LOADBF(nb)                                          \
    _Pragma("unroll") for (int kk = 0; kk < 4; ++kk) {      \
        int g = ((kk * 2 + half) ^ sw) * 8;                 \
        bf[0][kk] = *(const h8*)&Bs[nb][brow0 + g];         \
        bf[1][kk] = *(const h8*)&Bs[nb][brow1 + g];         \
    }

#define PH(nb, mi, STAGEM)                                                                             \
    {                                                                                                  \
        h8 af[4];                                                                                      \
        _Pragma("unroll") for (int kk = 0; kk < 4; ++kk)                                               \
            af[kk] = *(const h8*)&As[nb][((mi)*64 + arow) * 64 + ((kk * 2 + half) ^ sw) * 8];          \
        STAGEM;                                                                                        \
        __builtin_amdgcn_s_setprio(1);                                                                 \
        _Pragma("unroll") for (int kk = 0; kk < 4; ++kk) {                                             \
            acc[mi][0] = __builtin_amdgcn_mfma_f32_32x32x16_f16(af[kk], bf[0][kk], acc[mi][0], 0, 0, 0); \
            acc[mi][1] = __builtin_amdgcn_mfma_f32_32x32x16_f16(af[kk], bf[1][kk], acc[mi][1], 0, 0, 0); \
        }                                                                                              \
        __builtin_amdgcn_s_setprio(0);                                                                 \
    }

    // prologue: stage tile 0 into buf 0 (slot order B0,B1,A01,A23 — vmcnt counts depend on it)
    SB0(0, 0); SB1(0, 0); SA0(0, 0); SA1(0, 0);

    for (int t = 0; t < 15; ++t) {
        int nb = t & 1, kn = t * 64 + 64;
        SYNC(2);               // s0,s1,s2 of tile t landed; s3 may fly
        LOADBF(nb);
        PH(nb, 0, SB0(nb ^ 1, kn));
        PH(nb, 1, SB1(nb ^ 1, kn));
        SYNC(4);               // s3 of tile t landed; next B0,B1 fly
        PH(nb, 2, SA0(nb ^ 1, kn));
        PH(nb, 3, SA1(nb ^ 1, kn));
    }
    {   // t = 15 (no staging)
        SYNC(2);
        LOADBF(1);
        PH(1, 0, (void)0);
        PH(1, 1, (void)0);
        SYNC(0);
        PH(1, 2, (void)0);
        PH(1, 3, (void)0);
    }

    // epilogue: scatter to Qf/Kf/Vf fragment-native layouts (same mapping as v1, new tile geometry)
#pragma unroll
    for (int mi = 0; mi < 4; ++mi) {
#pragma unroll
        for (int ni = 0; ni < 2; ++ni) {
            const f32x16& a = acc[mi][ni];
            int n = n0 + wn * 64 + ni * 32 + l31;
            int mbase = m0 + wm * 128 + mi * 32;
            int bb = mbase >> 11, tb = mbase & 2047;
            float bv = bias[n];
            int n2 = n & 1023;
            int h = n2 >> 6, d = n2 & 63;
            if (n < 2048) {
                float sc = (n < 1024) ? 0.125f : 1.0f;
                u16* base = (n < 1024 ? Qf : Kf) +
                            (size_t)(bb * 16 + h) * 131072 + (tb >> 5) * 2048 + (d >> 3) * 256 + (d & 7);
#pragma unroll
                for (int r = 0; r < 16; ++r) {
                    int row = (r & 3) + 8 * (r >> 2) + 4 * half;
                    base[row * 8] = f2h_bits((a[r] + bv) * sc);
                }
            } else {
                u16* vbase = Vf + (size_t)(bb * 16 + h) * 131072 + (tb >> 5) * 2048 + d * 8 + 4 * half;
#pragma unroll
                for (int rq = 0; rq < 4; ++rq) {
                    u16 q4[4];
#pragma unroll
                    for (int j = 0; j < 4; ++j) q4[j] = f2h_bits(a[4 * rq + j] + bv);
                    *(ushort4*)(vbase + rq * 512) = *(ushort4*)q4;
                }
            }
        }
    }
#undef SB0
#undef SB1
#undef SA0
#undef SA1
#undef SYNC
#undef LOADBF
#undef PH
}

// ---------- attention v7: permlane32_swap pack, diagonal-only masking, 2-set rotation, parallel epilogue ----------
__global__ void __launch_bounds__(256) attn(const u16* __restrict__ Qf, const u16* __restrict__ Kf,
                                            const u16* __restrict__ Vf, float* __restrict__ out) {
    __shared__ float4 red[4 * 8 * 64];  // 32 KB
    int bh = blockIdx.x;                // fast dim: id%8 = bh%8 -> same-bh on one XCD
    int tt = 63 - blockIdx.y;           // heavy q-tiles dispatch first (better tail)
    int b = bh >> 4, h = bh & 15;
    int tid = threadIdx.x, w = tid >> 6, lane = tid & 63;
    int l31 = lane & 31, half = lane >> 5;

    const u16* Qbh = Qf + (size_t)bh * 131072;
    const u16* Kbh = Kf + (size_t)bh * 131072;
    const u16* Vbh = Vf + (size_t)bh * 131072;

    int qset = tt * 32;
    const u16* qp = Qbh + tt * 2048 + half * 256 + l31 * 8;
    h8 aQ[4];
#pragma unroll
    for (int kk = 0; kk < 4; ++kk) aQ[kk] = *(const h8*)(qp + kk * 512);

    int nkt = tt + 1;
    int kt0 = (nkt * w) >> 2;
    int kt1 = (nkt * (w + 1)) >> 2;
    f32x16 y0 = zero16(), y1 = zero16();
    int qg = qset + l31;

    auto LOADKV = [&](int kt, h8* Kd, h8* Vd) {
        const u16* kp = Kbh + kt * 2048 + half * 256 + l31 * 8;
        const u16* vp = Vbh + kt * 2048 + half * 512 + l31 * 8;
#pragma unroll
        for (int kk = 0; kk < 4; ++kk) Kd[kk] = *(const h8*)(kp + kk * 512);
        Vd[0] = *(const h8*)vp;
        Vd[1] = *(const h8*)(vp + 1024);
        Vd[2] = *(const h8*)(vp + 256);
        Vd[3] = *(const h8*)(vp + 1280);
    };

    auto TILE = [&](int kt, const h8* Kc, const h8* Vc) {
        f32x16 sT = zero16();
#pragma unroll
        for (int kk = 0; kk < 4; ++kk)
            sT = __builtin_amdgcn_mfma_f32_32x32x16_f16(Kc[kk], aQ[kk], sT, 0, 0, 0);

        u32 pk[8];
        if (kt == tt) {  // only the diagonal tile needs causal masking (wave-uniform branch)
            int cbase = qg - kt * 32 - 4 * half;
#pragma unroll
            for (int j = 0; j < 8; ++j) {
                int row0 = ((2 * j) & 3) + 8 * (j >> 1);
                float v0 = (row0 <= cbase) ? fmaxf(sT[2 * j], 0.f) : 0.f;
                float v1 = (row0 + 1 <= cbase) ? fmaxf(sT[2 * j + 1], 0.f) : 0.f;
                fp16x2 c2 = __builtin_amdgcn_cvt_pkrtz(v0, v1);
                __builtin_memcpy(&pk[j], &c2, 4);
            }
        } else {
#pragma unroll
            for (int j = 0; j < 8; ++j) {
                fp16x2 c2 = __builtin_amdgcn_cvt_pkrtz(fmaxf(sT[2 * j], 0.f), fmaxf(sT[2 * j + 1], 0.f));
                __builtin_memcpy(&pk[j], &c2, 4);
            }
        }
        // cross-half redistribution: one permlane32_swap fills two B-fragment words
        u32 a0 = pk[0], b0 = pk[2], a1 = pk[1], b1 = pk[3];
        u32 a2 = pk[4], b2 = pk[6], a3 = pk[5], b3 = pk[7];
        asm("v_permlane32_swap_b32 %0, %1" : "+v"(a0), "+v"(b0));
        asm("v_permlane32_swap_b32 %0, %1" : "+v"(a1), "+v"(b1));
        asm("v_permlane32_swap_b32 %0, %1" : "+v"(a2), "+v"(b2));
        asm("v_permlane32_swap_b32 %0, %1" : "+v"(a3), "+v"(b3));
        u32 f0[4] = {a0, a1, b0, b1};
        u32 f1[4] = {a2, a3, b2, b3};
        h8 bP0, bP1;
        __builtin_memcpy(&bP0, f0, 16);
        __builtin_memcpy(&bP1, f1, 16);

        y0 = __builtin_amdgcn_mfma_f32_32x32x16_f16(Vc[0], bP0, y0, 0, 0, 0);
        y0 = __builtin_amdgcn_mfma_f32_32x32x16_f16(Vc[1], bP1, y0, 0, 0, 0);
        y1 = __builtin_amdgcn_mfma_f32_32x32x16_f16(Vc[2], bP0, y1, 0, 0, 0);
        y1 = __builtin_amdgcn_mfma_f32_32x32x16_f16(Vc[3], bP1, y1, 0, 0, 0);
    };

    if (kt0 < kt1) {
        h8 KA[4], VA[4], KB[4], VB[4];
        LOADKV(kt0, KA, VA);
        for (int kt = kt0; kt < kt1; kt += 2) {
            int ktn = kt + 1 < kt1 ? kt + 1 : kt1 - 1;
            LOADKV(ktn, KB, VB);           // prefetch t+1 overlapped with compute(t)
            TILE(kt, KA, VA);
            int ktn2 = kt + 2 < kt1 ? kt + 2 : kt1 - 1;
            LOADKV(ktn2, KA, VA);          // prefetch t+2 overlapped with compute(t+1)
            if (kt + 1 < kt1) TILE(kt + 1, KB, VB);
        }
    }

    // parallel epilogue: all 4 waves dump y to LDS, then 256 threads sum+store
#pragma unroll
    for (int g = 0; g < 4; ++g) {
        red[(w * 8 + g) * 64 + lane] =
            make_float4(y0[4 * g], y0[4 * g + 1], y0[4 * g + 2], y0[4 * g + 3]);
        red[(w * 8 + 4 + g) * 64 + lane] =
            make_float4(y1[4 * g], y1[4 * g + 1], y1[4 * g + 2], y1[4 * g + 3]);
    }
    __syncthreads();
#pragma unroll
    for (int ss = 0; ss < 2; ++ss) {
        int s = tid + ss * 256;  // stride-16B across lanes: bank-conflict-free
        float4 r0 = red[s], r1 = red[512 + s], r2 = red[1024 + s], r3 = red[1536 + s];
        float4 acc = make_float4(r0.x + r1.x + r2.x + r3.x, r0.y + r1.y + r2.y + r3.y,
                                 r0.z + r1.z + r2.z + r3.z, r0.w + r1.w + r2.w + r3.w);
        int gslot = s >> 6, ln = s & 63;
        int sl31 = ln & 31, shf = ln >> 5;
        int d = (gslot >> 2) * 32 + (gslot & 3) * 8 + shf * 4;
        *(float4*)(out + ((size_t)b * 2048 + qset + sl31) * 1024 + h * 64 + d) = acc;
    }
}

extern "C" void kernel_launch(void* const* d_in, const int* in_sizes, int n_in,
                              void* d_out, int out_size, void* d_ws, size_t ws_size,
                              hipStream_t stream) {
    const float* X = (const float*)d_in[0];     // [2,2048,1024] f32 (fp16 values widened)
    const float* W = (const float*)d_in[1];     // [1024,3072] f32
    const float* bias = (const float*)d_in[2];  // [3072] f32
    float* out = (float*)d_out;                 // [2,2048,1024] f32

    char* ws = (char*)d_ws;
    u16* Xh = (u16*)ws;                      // 8388608 B
    u16* Wt = (u16*)(ws + 8388608);          // 6291456 B
    u16* Qf = (u16*)(ws + 14680064);         // 8388608 B
    u16* Kf = (u16*)(ws + 23068672);         // 8388608 B
    u16* Vf = (u16*)(ws + 31457280);         // 8388608 B

    prep<<<2816, 256, 0, stream>>>(X, W, Xh, Wt);
    qkv_gemm<<<dim3(16, 12), 512, 0, stream>>>(Xh, Wt, bias, Qf, Kf, Vf);
    attn<<<dim3(32, 64), 256, 0, stream>>>(Qf, Kf, Vf, out);
}

// Round 4
// 140.539 us; speedup vs baseline: 1.0332x; 1.0063x over previous
//
#include <hip/hip_runtime.h>

typedef unsigned short u16;
typedef unsigned int u32;
typedef _Float16 h8 __attribute__((ext_vector_type(8)));
typedef __fp16 fp16x2 __attribute__((ext_vector_type(2)));
typedef float f32x16 __attribute__((ext_vector_type(16)));

__device__ inline f32x16 zero16() {
    f32x16 v;
#pragma unroll
    for (int i = 0; i < 16; ++i) v[i] = 0.f;
    return v;
}
__device__ inline u16 f2h_bits(float f) {
    _Float16 h = (_Float16)f;
    u16 u;
    __builtin_memcpy(&u, &h, 2);
    return u;
}
__device__ inline void load_lds16(const u16* g, u16* l) {
    __builtin_amdgcn_global_load_lds((const __attribute__((address_space(1))) u32*)(const void*)g,
                                     (__attribute__((address_space(3))) u32*)(void*)l, 16, 0, 0);
}

// ---------- merged prep: X f32->f16 (blocks 0..2047), W f32 [1024][3072] -> Wt f16 [3072][1024] ----------
__global__ void __launch_bounds__(256) prep(const float* __restrict__ X, const float* __restrict__ W,
                                            u16* __restrict__ Xh, u16* __restrict__ Wt) {
    __shared__ __attribute__((aligned(16))) u16 tile[64][72];
    int bb = blockIdx.x;
    int tid = threadIdx.x;
    if (bb < 2048) {
        int i = (bb * 256 + tid) * 8;
        float4 a = *(const float4*)(X + i);
        float4 b = *(const float4*)(X + i + 4);
        u16 t[8] = {f2h_bits(a.x), f2h_bits(a.y), f2h_bits(a.z), f2h_bits(a.w),
                    f2h_bits(b.x), f2h_bits(b.y), f2h_bits(b.z), f2h_bits(b.w)};
        *(uint4*)(Xh + i) = *(uint4*)t;
        return;
    }
    bb -= 2048;
    int tn0 = (bb % 48) * 64, tk0 = (bb / 48) * 64;
#pragma unroll
    for (int i = 0; i < 4; ++i) {
        int e = (i * 256 + tid) * 4;
        int r = e >> 6, c = e & 63;
        float4 v = *(const float4*)(W + (size_t)(tk0 + r) * 3072 + tn0 + c);
        tile[r][c + 0] = f2h_bits(v.x);
        tile[r][c + 1] = f2h_bits(v.y);
        tile[r][c + 2] = f2h_bits(v.z);
        tile[r][c + 3] = f2h_bits(v.w);
    }
    __syncthreads();
#pragma unroll
    for (int i = 0; i < 2; ++i) {
        int e = (i * 256 + tid) * 8;
        int r = e >> 6, c = e & 63;
        u16 tmp[8];
#pragma unroll
        for (int j = 0; j < 8; ++j) tmp[j] = tile[c + j][r];
        *(uint4*)(Wt + (size_t)(tn0 + r) * 1024 + tk0 + c) = *(uint4*)tmp;
    }
}

// ---------- QKV GEMM v2: 256x256 tile, 8 waves (2Mx4N), 4-phase counted-vmcnt pipeline ----------
__global__ void __launch_bounds__(512, 2) qkv_gemm(const u16* __restrict__ Xh, const u16* __restrict__ Wt,
                                                   const float* __restrict__ bias, u16* __restrict__ Qf,
                                                   u16* __restrict__ Kf, u16* __restrict__ Vf) {
    __shared__ __attribute__((aligned(16))) u16 As[2][16384];  // 64 KB
    __shared__ __attribute__((aligned(16))) u16 Bs[2][16384];  // 64 KB
    int m0 = blockIdx.x * 256, n0 = blockIdx.y * 256;
    int tid = threadIdx.x, wave = tid >> 6, lane = tid & 63;
    int l31 = lane & 31, half = lane >> 5;
    int wm = wave & 1, wn = wave >> 1;  // 2M x 4N
    int sw = (l31 >> 1) & 7;

    int e0 = tid * 8, e1 = (512 + tid) * 8;
    int r0 = e0 >> 6, c0 = e0 & 63;
    int r1 = e1 >> 6, c1 = e1 & 63;
    int gs0 = ((c0 >> 3) ^ ((r0 >> 1) & 7)) * 8;
    int gs1 = ((c1 >> 3) ^ ((r1 >> 1) & 7)) * 8;
    int gr0 = ((r0 >> 5) & 1) * 128 + (r0 >> 6) * 32 + (r0 & 31);
    int gr1 = ((r1 >> 5) & 1) * 128 + (r1 >> 6) * 32 + (r1 & 31);
    const u16* pB0_0 = Wt + (size_t)(n0 + r0) * 1024 + gs0;
    const u16* pB0_1 = Wt + (size_t)(n0 + r1) * 1024 + gs1;
    const u16* pB1_0 = pB0_0 + 128 * 1024;
    const u16* pB1_1 = pB0_1 + 128 * 1024;
    const u16* pA0_0 = Xh + (size_t)(m0 + gr0) * 1024 + gs0;
    const u16* pA0_1 = Xh + (size_t)(m0 + gr1) * 1024 + gs1;
    const u16* pA1_0 = pA0_0 + 64 * 1024;
    const u16* pA1_1 = pA0_1 + 64 * 1024;

#define SB0(nb, ko) { load_lds16(pB0_0 + (ko), &Bs[nb][e0]); load_lds16(pB0_1 + (ko), &Bs[nb][e1]); }
#define SB1(nb, ko) { load_lds16(pB1_0 + (ko), &Bs[nb][8192 + e0]); load_lds16(pB1_1 + (ko), &Bs[nb][8192 + e1]); }
#define SA0(nb, ko) { load_lds16(pA0_0 + (ko), &As[nb][e0]); load_lds16(pA0_1 + (ko), &As[nb][e1]); }
#define SA1(nb, ko) { load_lds16(pA1_0 + (ko), &As[nb][8192 + e0]); load_lds16(pA1_1 + (ko), &As[nb][8192 + e1]); }

#define SYNC(n)                                           \
    __builtin_amdgcn_sched_barrier(0);                    \
    asm volatile("s_waitcnt vmcnt(" #n ")" ::: "memory"); \
    __builtin_amdgcn_s_barrier();                         \
    __builtin_amdgcn_sched_barrier(0);

    int arow = wm * 32 + l31;
    int brow0 = (wn * 64 + l31) * 64;
    int brow1 = (wn * 64 + 32 + l31) * 64;

    f32x16 acc[4][2];
#pragma unroll
    for (int mi = 0; mi < 4; ++mi) {
        acc[mi][0] = zero16();
        acc[mi][1] = zero16();
    }
    h8 bf[2][4];

#define LOADBF(nb)                                          \
    _Pragma("unroll") for (int kk = 0; kk < 4; ++kk) {      \
        int g = ((kk * 2 + half) ^ sw) * 8;                 \
        bf[0][kk] = *(const h8*)&Bs[nb][brow0 + g];         \
        bf[1][kk] = *(const h8*)&Bs[nb][brow1 + g];         \
    }

#define PH(nb, mi, STAGEM)                                                                             \
    {                                                                                                  \
        h8 af[4];                                                                                      \
        _Pragma("unroll") for (int kk = 0; kk < 4; ++kk)                                               \
            af[kk] = *(const h8*)&As[nb][((mi)*64 + arow) * 64 + ((kk * 2 + half) ^ sw) * 8];          \
        STAGEM;                                                                                        \
        __builtin_amdgcn_s_setprio(1);                                                                 \
        _Pragma("unroll") for (int kk = 0; kk < 4; ++kk) {                                             \
            acc[mi][0] = __builtin_amdgcn_mfma_f32_32x32x16_f16(af[kk], bf[0][kk], acc[mi][0], 0, 0, 0); \
            acc[mi][1] = __builtin_amdgcn_mfma_f32_32x32x16_f16(af[kk], bf[1][kk], acc[mi][1], 0, 0, 0); \
        }                                                                                              \
        __builtin_amdgcn_s_setprio(0);                                                                 \
    }

    SB0(0, 0); SB1(0, 0); SA0(0, 0); SA1(0, 0);

    for (int t = 0; t < 15; ++t) {
        int nb = t & 1, kn = t * 64 + 64;
        SYNC(2);
        LOADBF(nb);
        PH(nb, 0, SB0(nb ^ 1, kn));
        PH(nb, 1, SB1(nb ^ 1, kn));
        SYNC(4);
        PH(nb, 2, SA0(nb ^ 1, kn));
        PH(nb, 3, SA1(nb ^ 1, kn));
    }
    {
        SYNC(2);
        LOADBF(1);
        PH(1, 0, (void)0);
        PH(1, 1, (void)0);
        SYNC(0);
        PH(1, 2, (void)0);
        PH(1, 3, (void)0);
    }

#pragma unroll
    for (int mi = 0; mi < 4; ++mi) {
#pragma unroll
        for (int ni = 0; ni < 2; ++ni) {
            const f32x16& a = acc[mi][ni];
            int n = n0 + wn * 64 + ni * 32 + l31;
            int mbase = m0 + wm * 128 + mi * 32;
            int bb = mbase >> 11, tb = mbase & 2047;
            float bv = bias[n];
            int n2 = n & 1023;
            int h = n2 >> 6, d = n2 & 63;
            if (n < 2048) {
                float sc = (n < 1024) ? 0.125f : 1.0f;
                u16* base = (n < 1024 ? Qf : Kf) +
                            (size_t)(bb * 16 + h) * 131072 + (tb >> 5) * 2048 + (d >> 3) * 256 + (d & 7);
#pragma unroll
                for (int r = 0; r < 16; ++r) {
                    int row = (r & 3) + 8 * (r >> 2) + 4 * half;
                    base[row * 8] = f2h_bits((a[r] + bv) * sc);
                }
            } else {
                u16* vbase = Vf + (size_t)(bb * 16 + h) * 131072 + (tb >> 5) * 2048 + d * 8 + 4 * half;
#pragma unroll
                for (int rq = 0; rq < 4; ++rq) {
                    u16 q4[4];
#pragma unroll
                    for (int j = 0; j < 4; ++j) q4[j] = f2h_bits(a[4 * rq + j] + bv);
                    *(ushort4*)(vbase + rq * 512) = *(ushort4*)q4;
                }
            }
        }
    }
#undef SB0
#undef SB1
#undef SA0
#undef SA1
#undef SYNC
#undef LOADBF
#undef PH
}

// ---------- attention v8: 2 q-tiles per block (halved K/V L2 traffic), permlane pack, mode-coded causal ----------
__global__ void __launch_bounds__(256, 2) attn(const u16* __restrict__ Qf, const u16* __restrict__ Kf,
                                               const u16* __restrict__ Vf, float* __restrict__ out) {
    __shared__ float4 red[4 * 8 * 64];  // 32 KB (reused across two reduction passes)
    int bh = blockIdx.x;                // fast dim: bh%8 -> XCD affinity, same-bh K/V shares L2
    int tp = 31 - blockIdx.y;           // q-pair 0..31, heavy pairs dispatch first
    int b = bh >> 4, h = bh & 15;
    int tid = threadIdx.x, w = tid >> 6, lane = tid & 63;
    int l31 = lane & 31, half = lane >> 5;

    const u16* Qbh = Qf + (size_t)bh * 131072;
    const u16* Kbh = Kf + (size_t)bh * 131072;
    const u16* Vbh = Vf + (size_t)bh * 131072;

    int qa = 2 * tp, qb = 2 * tp + 1;   // the two q-tiles (32 rows each)
    const u16* qpA = Qbh + qa * 2048 + half * 256 + l31 * 8;
    const u16* qpB = Qbh + qb * 2048 + half * 256 + l31 * 8;
    h8 aQA[4], aQB[4];
#pragma unroll
    for (int kk = 0; kk < 4; ++kk) {
        aQA[kk] = *(const h8*)(qpA + kk * 512);
        aQB[kk] = *(const h8*)(qpB + kk * 512);
    }

    int nkt = qb + 1;
    int kt0 = (nkt * w) >> 2;
    int kt1 = (nkt * (w + 1)) >> 2;
    f32x16 yA0 = zero16(), yA1 = zero16(), yB0 = zero16(), yB1 = zero16();

    auto LOADKV = [&](int kt, h8* Kd, h8* Vd) {
        const u16* kp = Kbh + kt * 2048 + half * 256 + l31 * 8;
        const u16* vp = Vbh + kt * 2048 + half * 512 + l31 * 8;
#pragma unroll
        for (int kk = 0; kk < 4; ++kk) Kd[kk] = *(const h8*)(kp + kk * 512);
        Vd[0] = *(const h8*)vp;
        Vd[1] = *(const h8*)(vp + 1024);
        Vd[2] = *(const h8*)(vp + 256);
        Vd[3] = *(const h8*)(vp + 1280);
    };

    auto PACK = [&](const f32x16& sT, int cbase, bool masked, h8& bP0, h8& bP1) {
        u32 pk[8];
        if (masked) {  // wave-uniform: diagonal tiles only
#pragma unroll
            for (int j = 0; j < 8; ++j) {
                int row0 = ((2 * j) & 3) + 8 * (j >> 1);
                float v0 = (row0 <= cbase) ? fmaxf(sT[2 * j], 0.f) : 0.f;
                float v1 = (row0 + 1 <= cbase) ? fmaxf(sT[2 * j + 1], 0.f) : 0.f;
                fp16x2 c2 = __builtin_amdgcn_cvt_pkrtz(v0, v1);
                __builtin_memcpy(&pk[j], &c2, 4);
            }
        } else {
#pragma unroll
            for (int j = 0; j < 8; ++j) {
                fp16x2 c2 = __builtin_amdgcn_cvt_pkrtz(fmaxf(sT[2 * j], 0.f), fmaxf(sT[2 * j + 1], 0.f));
                __builtin_memcpy(&pk[j], &c2, 4);
            }
        }
        u32 a0 = pk[0], b0 = pk[2], a1 = pk[1], b1 = pk[3];
        u32 a2 = pk[4], b2 = pk[6], a3 = pk[5], b3 = pk[7];
        asm("v_permlane32_swap_b32 %0, %1" : "+v"(a0), "+v"(b0));
        asm("v_permlane32_swap_b32 %0, %1" : "+v"(a1), "+v"(b1));
        asm("v_permlane32_swap_b32 %0, %1" : "+v"(a2), "+v"(b2));
        asm("v_permlane32_swap_b32 %0, %1" : "+v"(a3), "+v"(b3));
        u32 f0[4] = {a0, a1, b0, b1};
        u32 f1[4] = {a2, a3, b2, b3};
        __builtin_memcpy(&bP0, f0, 16);
        __builtin_memcpy(&bP1, f1, 16);
    };

    // mode: 0 = interior (A full, B full), 1 = kt==qa (A diag, B full), 2 = kt==qb (A skip, B diag)
    auto TILE = [&](int kt, int md, const h8* Kc, const h8* Vc) {
        h8 bP0, bP1;
        if (md != 2) {
            f32x16 sT = zero16();
#pragma unroll
            for (int kk = 0; kk < 4; ++kk)
                sT = __builtin_amdgcn_mfma_f32_32x32x16_f16(Kc[kk], aQA[kk], sT, 0, 0, 0);
            PACK(sT, 64 * tp + l31 - kt * 32 - 4 * half, md == 1, bP0, bP1);
            yA0 = __builtin_amdgcn_mfma_f32_32x32x16_f16(Vc[0], bP0, yA0, 0, 0, 0);
            yA0 = __builtin_amdgcn_mfma_f32_32x32x16_f16(Vc[1], bP1, yA0, 0, 0, 0);
            yA1 = __builtin_amdgcn_mfma_f32_32x32x16_f16(Vc[2], bP0, yA1, 0, 0, 0);
            yA1 = __builtin_amdgcn_mfma_f32_32x32x16_f16(Vc[3], bP1, yA1, 0, 0, 0);
        }
        {
            f32x16 sT = zero16();
#pragma unroll
            for (int kk = 0; kk < 4; ++kk)
                sT = __builtin_amdgcn_mfma_f32_32x32x16_f16(Kc[kk], aQB[kk], sT, 0, 0, 0);
            PACK(sT, 64 * tp + 32 + l31 - kt * 32 - 4 * half, md == 2, bP0, bP1);
            yB0 = __builtin_amdgcn_mfma_f32_32x32x16_f16(Vc[0], bP0, yB0, 0, 0, 0);
            yB0 = __builtin_amdgcn_mfma_f32_32x32x16_f16(Vc[1], bP1, yB0, 0, 0, 0);
            yB1 = __builtin_amdgcn_mfma_f32_32x32x16_f16(Vc[2], bP0, yB1, 0, 0, 0);
            yB1 = __builtin_amdgcn_mfma_f32_32x32x16_f16(Vc[3], bP1, yB1, 0, 0, 0);
        }
    };

    if (kt0 < kt1) {
        h8 KA[4], VA[4], KB[4], VB[4];
        LOADKV(kt0, KA, VA);
        for (int kt = kt0; kt < kt1; kt += 2) {
            int ktn = kt + 1 < kt1 ? kt + 1 : kt1 - 1;
            LOADKV(ktn, KB, VB);  // prefetch t+1 overlapped with compute(t)
            int md0 = (kt == qa) ? 1 : (kt == qb ? 2 : 0);
            TILE(kt, md0, KA, VA);
            int ktn2 = kt + 2 < kt1 ? kt + 2 : kt1 - 1;
            LOADKV(ktn2, KA, VA);  // prefetch t+2 overlapped with compute(t+1)
            if (kt + 1 < kt1) {
                int md1 = (kt + 1 == qa) ? 1 : (kt + 1 == qb ? 2 : 0);
                TILE(kt + 1, md1, KB, VB);
            }
        }
    }

    // two-pass parallel epilogue (reuses the 32 KB red buffer)
#pragma unroll 2
    for (int pass = 0; pass < 2; ++pass) {
        const f32x16& z0 = pass ? yB0 : yA0;
        const f32x16& z1 = pass ? yB1 : yA1;
        if (pass) __syncthreads();  // pass-0 reads done before overwrite
#pragma unroll
        for (int g = 0; g < 4; ++g) {
            red[(w * 8 + g) * 64 + lane] =
                make_float4(z0[4 * g], z0[4 * g + 1], z0[4 * g + 2], z0[4 * g + 3]);
            red[(w * 8 + 4 + g) * 64 + lane] =
                make_float4(z1[4 * g], z1[4 * g + 1], z1[4 * g + 2], z1[4 * g + 3]);
        }
        __syncthreads();
#pragma unroll
        for (int ss = 0; ss < 2; ++ss) {
            int s = tid + ss * 256;  // stride-16B across lanes: bank-conflict-free
            float4 r0 = red[s], r1 = red[512 + s], r2 = red[1024 + s], r3 = red[1536 + s];
            float4 acc = make_float4(r0.x + r1.x + r2.x + r3.x, r0.y + r1.y + r2.y + r3.y,
                                     r0.z + r1.z + r2.z + r3.z, r0.w + r1.w + r2.w + r3.w);
            int gslot = s >> 6, ln = s & 63;
            int sl31 = ln & 31, shf = ln >> 5;
            int d = (gslot >> 2) * 32 + (gslot & 3) * 8 + shf * 4;
            int row = 64 * tp + pass * 32 + sl31;
            *(float4*)(out + ((size_t)b * 2048 + row) * 1024 + h * 64 + d) = acc;
        }
    }
}

extern "C" void kernel_launch(void* const* d_in, const int* in_sizes, int n_in,
                              void* d_out, int out_size, void* d_ws, size_t ws_size,
                              hipStream_t stream) {
    const float* X = (const float*)d_in[0];     // [2,2048,1024] f32 (fp16 values widened)
    const float* W = (const float*)d_in[1];     // [1024,3072] f32
    const float* bias = (const float*)d_in[2];  // [3072] f32
    float* out = (float*)d_out;                 // [2,2048,1024] f32

    char* ws = (char*)d_ws;
    u16* Xh = (u16*)ws;                      // 8388608 B
    u16* Wt = (u16*)(ws + 8388608);          // 6291456 B
    u16* Qf = (u16*)(ws + 14680064);         // 8388608 B
    u16* Kf = (u16*)(ws + 23068672);         // 8388608 B
    u16* Vf = (u16*)(ws + 31457280);         // 8388608 B

    prep<<<2816, 256, 0, stream>>>(X, W, Xh, Wt);
    qkv_gemm<<<dim3(16, 12), 512, 0, stream>>>(Xh, Wt, bias, Qf, Kf, Vf);
    attn<<<dim3(32, 32), 256, 0, stream>>>(Qf, Kf, Vf, out);
}